// Round 4
// baseline (675.596 us; speedup 1.0000x reference)
//
#include <hip/hip_runtime.h>
#include <hip/hip_bf16.h>

#define NN 100000
#define NE 1250000
#define DD 64
#define RR 16
#define NSLOT 9          // group0: W0..W7 + self ; group1 reuses slots 0..7
#define NTILE 6250       // NN/16
#define NBINS 200000     // dst*2 + relgroup
#define NBLK2 782        // ceil(NBINS/256)

typedef __attribute__((ext_vector_type(8))) short s16x8;
typedef __attribute__((ext_vector_type(4))) float f32x4;

static __device__ __forceinline__ unsigned short f2bf(float v) {
    __hip_bfloat16 h = __float2bfloat16(v);
    return __builtin_bit_cast(unsigned short, h);
}
static __device__ __forceinline__ float bf2f(unsigned short u) {
    unsigned int w = ((unsigned int)u) << 16;
    return __builtin_bit_cast(float, w);
}
static __device__ __forceinline__ unsigned int pack2(float a, float b) {
    return ((unsigned int)f2bf(b) << 16) | (unsigned int)f2bf(a);
}

// ---------------- sort by (dst, relgroup) : counting sort, 200k bins ----------------

__global__ void hist_key(const int* __restrict__ dst, const int* __restrict__ et,
                         int* __restrict__ cnt) {
    int e = blockIdx.x * 256 + threadIdx.x;
    if (e < NE) atomicAdd(&cnt[dst[e] * 2 + (et[e] >> 3)], 1);
}

__global__ __launch_bounds__(256) void scan1(const int* __restrict__ cnt,
                                             int* __restrict__ rp, int* __restrict__ part) {
    __shared__ int s[256];
    int i = blockIdx.x * 256 + threadIdx.x;
    int v = (i < NBINS) ? cnt[i] : 0;
    s[threadIdx.x] = v;
    __syncthreads();
    for (int off = 1; off < 256; off <<= 1) {
        int t = (threadIdx.x >= off) ? s[threadIdx.x - off] : 0;
        __syncthreads();
        s[threadIdx.x] += t;
        __syncthreads();
    }
    if (i < NBINS) rp[i] = s[threadIdx.x] - v;        // exclusive
    if (threadIdx.x == 255) part[blockIdx.x] = s[255];
}

__global__ __launch_bounds__(1024) void scan2(int* __restrict__ part, int* __restrict__ rp) {
    __shared__ int s[NBLK2];
    if (threadIdx.x < NBLK2) s[threadIdx.x] = part[threadIdx.x];
    __syncthreads();
    if (threadIdx.x == 0) {
        int acc = 0;
        for (int b = 0; b < NBLK2; ++b) { int t = s[b]; s[b] = acc; acc += t; }
        rp[NBINS] = NE;
    }
    __syncthreads();
    if (threadIdx.x < NBLK2) part[threadIdx.x] = s[threadIdx.x];
}

__global__ void scan3(int* __restrict__ rp, const int* __restrict__ part, int* __restrict__ cur) {
    int i = blockIdx.x * 256 + threadIdx.x;
    if (i < NBINS) {
        int v = rp[i] + part[blockIdx.x];
        rp[i] = v;
        cur[i] = v;
    }
}

// sg[p] = (rel&7)*NN + src  (slot-row index into the [9][N] table)
__global__ void scatter_key(const int* __restrict__ src, const int* __restrict__ dst,
                            const int* __restrict__ et, int* __restrict__ cur,
                            int* __restrict__ sg) {
    int e = blockIdx.x * 256 + threadIdx.x;
    if (e >= NE) return;
    int r = et[e];
    int p = atomicAdd(&cur[dst[e] * 2 + (r >> 3)], 1);
    sg[p] = (r & 7) * NN + src[e];
}

// ---------------- precision prep ----------------

// slots per layer: 0..7 = W0..W7, 8 = sw, 9..16 = W8..W15
// wt2[l][slot][o][d] = bf16( plane[d][o] )
__global__ void prep_w2(const float* __restrict__ W1, const float* __restrict__ sw1,
                        const float* __restrict__ W2, const float* __restrict__ sw2,
                        unsigned short* __restrict__ wt) {
    int i = blockIdx.x * 256 + threadIdx.x;
    if (i >= 2 * 17 * DD * DD) return;
    int d = i & 63;
    int o = (i >> 6) & 63;
    int s = (i >> 12) % 17;
    int l = i / (17 * DD * DD);
    const float* W  = l ? W2 : W1;
    const float* sw = l ? sw2 : sw1;
    const float* srcp;
    if (s < 8)       srcp = W + s * DD * DD;
    else if (s == 8) srcp = sw;
    else             srcp = W + (s - 1) * DD * DD;
    wt[i] = f2bf(srcp[d * DD + o]);
}

__global__ void prep_x2(const float* __restrict__ x, unsigned short* __restrict__ xb) {
    int i = blockIdx.x * blockDim.x + threadIdx.x;
    if (i < NN * DD) xb[i] = f2bf(x[i]);
}

// ---------------- kernel A: dense table  tab[slot][n][o] ----------------
// Transposed compute: C = Wp^T (A, m=o) x X^T (B, n=node); packed 8B stores.
__global__ __launch_bounds__(256) void xw_kernel(
    const unsigned short* __restrict__ xb,   // [N][64] bf16  (B: [k=d][n=node])
    const unsigned short* __restrict__ wt,   // [np][64][64] bf16 (A: [m=o][k=d])
    unsigned short* __restrict__ tab,        // [np][N][64] bf16
    int np)
{
    const int wid  = threadIdx.x >> 6;
    const int lane = threadIdx.x & 63;
    const int c = lane & 15;       // node within tile
    const int q = lane >> 4;
    const int t = blockIdx.x * 4 + wid;
    if (t >= NTILE) return;
    const int n0 = t * 16;
    const int p0 = blockIdx.y * 3;
    const int p1 = min(p0 + 3, np);

    const unsigned short* xrow = xb + (size_t)(n0 + c) * DD + q * 8;
    s16x8 b0 = *(const s16x8*)(xrow);
    s16x8 b1 = *(const s16x8*)(xrow + 32);

    for (int p = p0; p < p1; ++p) {
        const unsigned short* wp = wt + p * (DD * DD);
        uint2* orow = (uint2*)(tab + ((size_t)p * NN + n0 + c) * DD);
        #pragma unroll
        for (int nb = 0; nb < 4; ++nb) {
            const unsigned short* wrow = wp + (nb * 16 + c) * DD + q * 8;
            s16x8 a0 = *(const s16x8*)(wrow);
            s16x8 a1 = *(const s16x8*)(wrow + 32);
            f32x4 acc = {0.f, 0.f, 0.f, 0.f};
            acc = __builtin_amdgcn_mfma_f32_16x16x32_bf16(a0, b0, acc, 0, 0, 0);
            acc = __builtin_amdgcn_mfma_f32_16x16x32_bf16(a1, b1, acc, 0, 0, 0);
            uint2 pk;
            pk.x = pack2(acc[0], acc[1]);
            pk.y = pack2(acc[2], acc[3]);
            orow[nb * 4 + q] = pk;
        }
    }
}

// ---------------- kernel B: per-dst segment sum, two phases ----------------
// phase 0: acc = bias + self(slot 8) (+ xres) + edges(group0); carry[n] = acc
// phase 1: acc = carry + edges(group1); relu; -> outb / outf
__global__ __launch_bounds__(256) void agg_kernel(
    const unsigned short* __restrict__ tab,  // [9][N][64] bf16
    const int* __restrict__ rp2,             // [NBINS+1]
    const int* __restrict__ sg,              // [E] slot-row = (rel&7)*NN+src
    int phase,
    const float* __restrict__ bias,          // phase 0 only
    const float* __restrict__ xres,          // phase 0, layer 1 only (or null)
    float* __restrict__ carry,               // [N][64] fp32
    unsigned short* __restrict__ outb,       // phase 1, layer 1
    float* __restrict__ outf)                // phase 1, layer 2
{
    const int wid  = threadIdx.x >> 6;
    const int lane = threadIdx.x & 63;
    const int n = blockIdx.x * 4 + wid;      // 25000*4 == NN exactly
    const int h  = lane >> 5;                // half-wave id
    const int ol = lane & 31;                // o-pair index

    float a0 = 0.f, a1 = 0.f;
    int e = rp2[n * 2 + phase];
    const int e1 = rp2[n * 2 + phase + 1];
    for (; e + 4 <= e1; e += 4) {
        int r0 = sg[e + h];
        int r1 = sg[e + 2 + h];
        unsigned int u0 = *(const unsigned int*)(tab + (size_t)r0 * DD + ol * 2);
        unsigned int u1 = *(const unsigned int*)(tab + (size_t)r1 * DD + ol * 2);
        a0 += bf2f((unsigned short)u0) + bf2f((unsigned short)u1);
        a1 += bf2f((unsigned short)(u0 >> 16)) + bf2f((unsigned short)(u1 >> 16));
    }
    for (; e + 2 <= e1; e += 2) {
        int r0 = sg[e + h];
        unsigned int u0 = *(const unsigned int*)(tab + (size_t)r0 * DD + ol * 2);
        a0 += bf2f((unsigned short)u0);
        a1 += bf2f((unsigned short)(u0 >> 16));
    }
    if (e < e1 && h == 0) {
        int r0 = sg[e];
        unsigned int u0 = *(const unsigned int*)(tab + (size_t)r0 * DD + ol * 2);
        a0 += bf2f((unsigned short)u0);
        a1 += bf2f((unsigned short)(u0 >> 16));
    }
    a0 += __shfl_xor(a0, 32, 64);
    a1 += __shfl_xor(a1, 32, 64);

    if (phase == 0) {
        // self plane (slot 8) + bias (+ residual)
        unsigned int u = *(const unsigned int*)(tab + ((size_t)8 * NN + n) * DD + ol * 2);
        a0 += bf2f((unsigned short)u);
        a1 += bf2f((unsigned short)(u >> 16));
        const float2 bv = *(const float2*)(bias + ol * 2);
        a0 += bv.x; a1 += bv.y;
        if (xres) {
            const float2 rv = *(const float2*)(xres + (size_t)n * DD + ol * 2);
            a0 += rv.x; a1 += rv.y;
        }
        if (h == 0) {
            float2 v = {a0, a1};
            *(float2*)(carry + (size_t)n * DD + ol * 2) = v;
        }
    } else {
        const float2 cv = *(const float2*)(carry + (size_t)n * DD + ol * 2);
        a0 += cv.x; a1 += cv.y;
        a0 = fmaxf(a0, 0.f);
        a1 = fmaxf(a1, 0.f);
        if (h == 0) {
            if (outb)
                *(unsigned int*)(outb + (size_t)n * DD + ol * 2) = pack2(a0, a1);
            if (outf) {
                float2 v = {a0, a1};
                *(float2*)(outf + (size_t)n * DD + ol * 2) = v;
            }
        }
    }
}

// ================= launch =================

extern "C" void kernel_launch(void* const* d_in, const int* in_sizes, int n_in,
                              void* d_out, int out_size, void* d_ws, size_t ws_size,
                              hipStream_t stream)
{
    (void)in_sizes; (void)n_in; (void)out_size; (void)ws_size;
    const float* x    = (const float*)d_in[0];
    const int*   ei   = (const int*)d_in[1];
    const int*   et   = (const int*)d_in[2];
    const float* W1   = (const float*)d_in[3];
    const float* sw1  = (const float*)d_in[4];
    const float* b1   = (const float*)d_in[5];
    const float* W2   = (const float*)d_in[6];
    const float* sw2  = (const float*)d_in[7];
    const float* b2   = (const float*)d_in[8];
    float* out = (float*)d_out;

    const int* src = ei;
    const int* dst = ei + NE;

    char* ws = (char*)d_ws;

    // workspace layout (~174 MB of the ~250 MB verified available)
    unsigned short* tab   = (unsigned short*)(ws);                 // 115,200,000
    unsigned short* xb    = (unsigned short*)(ws + 115200000);     //  12,800,000
    unsigned short* h1b   = (unsigned short*)(ws + 128000000);     //  12,800,000
    float*          carry = (float*)(ws + 140800000);              //  25,600,000
    unsigned short* wt2   = (unsigned short*)(ws + 166400000);     //     278,528
    int* sg   = (int*)(ws + 166678528);                            //   5,000,000
    int* rp2  = (int*)(ws + 171678528);                            //     800,004
    int* cur  = (int*)(ws + 172478532);                            //     800,000
    int* cnt  = (int*)(ws + 173278532);                            //     800,000
    int* part = (int*)(ws + 174078532);                            //       3,128

    const int NB_E    = (NE + 255) / 256;        // 4883
    const int NB_ELEM = (NN * DD + 255) / 256;   // 25000

    // sort edges by (dst, relgroup) — once, reused by both layers
    hipMemsetAsync(cnt, 0, NBINS * sizeof(int), stream);
    hist_key<<<NB_E, 256, 0, stream>>>(dst, et, cnt);
    scan1<<<NBLK2, 256, 0, stream>>>(cnt, rp2, part);
    scan2<<<1, 1024, 0, stream>>>(part, rp2);
    scan3<<<NBLK2, 256, 0, stream>>>(rp2, part, cur);
    scatter_key<<<NB_E, 256, 0, stream>>>(src, dst, et, cur, sg);

    // precision prep
    prep_w2<<<(2 * 17 * DD * DD + 255) / 256, 256, 0, stream>>>(W1, sw1, W2, sw2, wt2);
    prep_x2<<<NB_ELEM, 256, 0, stream>>>(x, xb);

    const int NB_XW  = (NTILE + 3) / 4;          // 1563
    const int NB_AGG = NN / 4;                   // 25000
    const int WPL = 17 * DD * DD;                // wt2 stride per layer

    // ---- layer 1 (residual) ----
    xw_kernel<<<dim3(NB_XW, 3), 256, 0, stream>>>(xb, wt2, tab, 9);
    agg_kernel<<<NB_AGG, 256, 0, stream>>>(tab, rp2, sg, 0, b1, x, carry, nullptr, nullptr);
    xw_kernel<<<dim3(NB_XW, 3), 256, 0, stream>>>(xb, wt2 + 9 * DD * DD, tab, 8);
    agg_kernel<<<NB_AGG, 256, 0, stream>>>(tab, rp2, sg, 1, nullptr, nullptr, carry, h1b, nullptr);

    // ---- layer 2 (no residual) ----
    xw_kernel<<<dim3(NB_XW, 3), 256, 0, stream>>>(h1b, wt2 + WPL, tab, 9);
    agg_kernel<<<NB_AGG, 256, 0, stream>>>(tab, rp2, sg, 0, b2, nullptr, carry, nullptr, nullptr);
    xw_kernel<<<dim3(NB_XW, 3), 256, 0, stream>>>(h1b, wt2 + WPL + 9 * DD * DD, tab, 8);
    agg_kernel<<<NB_AGG, 256, 0, stream>>>(tab, rp2, sg, 1, nullptr, nullptr, carry, nullptr, out);
}